// Round 2
// baseline (2466.490 us; speedup 1.0000x reference)
//
#include <hip/hip_runtime.h>
#include <hip/hip_bf16.h>
#include <math.h>

// Problem constants
#define BB 16
#define SS 1024
#define DIN 768
#define DOUT 768
#define NH 12
#define HDIM 64
// M = BB*SS = 16384 rows

#define BHSD (BB * NH * SS * HDIM)   // 12,582,912 elements per Q/K/V buffer

// ---------------------------------------------------------------------------
// Kernel 1: fused QKV projection GEMM.
//   C[m][n] = sum_k X[m][k] * W[k][n]
//   written to (B,H,S,HD) layout: out[((b*NH+h)*SS+s)*HDIM + hd]
//   BM=128, BN=64, BK=16; block (16,16); thread tile 8x4.
// ---------------------------------------------------------------------------
__global__ __launch_bounds__(256) void qkv_gemm_kernel(
    const float* __restrict__ x,
    const float* __restrict__ wq, const float* __restrict__ wk,
    const float* __restrict__ wv,
    float* __restrict__ qb, float* __restrict__ kb, float* __restrict__ vb)
{
    const float* w  = (blockIdx.z == 0) ? wq : (blockIdx.z == 1) ? wk : wv;
    float* outb     = (blockIdx.z == 0) ? qb : (blockIdx.z == 1) ? kb : vb;

    __shared__ float As[16][128 + 1];  // [k][m], padded: reads are 2-way max (free)
    __shared__ float Bs[16][64 + 1];   // [k][n]

    const int tx = threadIdx.x;        // 0..15
    const int ty = threadIdx.y;        // 0..15
    const int tid = ty * 16 + tx;

    const int m0 = blockIdx.x * 128;
    const int n0 = blockIdx.y * 64;

    float acc[8][4] = {};

    for (int k0 = 0; k0 < DIN; k0 += 16) {
        // A tile: 128x16 = 2048 floats, 2 float4 per thread, stored transposed
        #pragma unroll
        for (int l = 0; l < 2; ++l) {
            int f   = tid + l * 256;       // float4 index in tile
            int row = f >> 2;              // 4 float4 per row of 16
            int c4  = (f & 3) * 4;
            float4 av = *reinterpret_cast<const float4*>(
                &x[(m0 + row) * DIN + k0 + c4]);
            As[c4 + 0][row] = av.x;
            As[c4 + 1][row] = av.y;
            As[c4 + 2][row] = av.z;
            As[c4 + 3][row] = av.w;
        }
        // B tile: 16x64 = 1024 floats, 1 float4 per thread
        {
            int row = tid >> 4;            // 16 float4 per row of 64
            int c4  = (tid & 15) * 4;
            float4 bv = *reinterpret_cast<const float4*>(
                &w[(k0 + row) * DOUT + n0 + c4]);
            Bs[row][c4 + 0] = bv.x;
            Bs[row][c4 + 1] = bv.y;
            Bs[row][c4 + 2] = bv.z;
            Bs[row][c4 + 3] = bv.w;
        }
        __syncthreads();

        #pragma unroll
        for (int k = 0; k < 16; ++k) {
            float a[8], b[4];
            #pragma unroll
            for (int i = 0; i < 8; ++i) a[i] = As[k][ty * 8 + i];
            #pragma unroll
            for (int j = 0; j < 4; ++j) b[j] = Bs[k][tx * 4 + j];
            #pragma unroll
            for (int i = 0; i < 8; ++i)
                #pragma unroll
                for (int j = 0; j < 4; ++j)
                    acc[i][j] = fmaf(a[i], b[j], acc[i][j]);
        }
        __syncthreads();
    }

    // Write in (B,H,S,HD) layout
    #pragma unroll
    for (int i = 0; i < 8; ++i) {
        int m = m0 + ty * 8 + i;
        int b = m >> 10;            // m / SS
        int s = m & 1023;           // m % SS
        #pragma unroll
        for (int j = 0; j < 4; ++j) {
            int n  = n0 + tx * 4 + j;
            int h  = n >> 6;        // n / HDIM
            int hd = n & 63;        // n % HDIM
            outb[((b * NH + h) * SS + s) * HDIM + hd] = acc[i][j];
        }
    }
}

// ---------------------------------------------------------------------------
// Kernel 2: flash attention. One block = one (b,h) pair x one 64-row Q tile.
//   256 threads as (tx,ty) 16x16; thread owns 4x4 of the 64x64 score tile
//   (rows ty*4+i, cols tx*4+j) and 4x4 of the 64x64 ctx tile.
//   Online softmax: per-row m/l kept redundantly by the 16 lanes sharing ty.
//   LDS: 4 x 64x65 f32 = 65 KB -> 2 blocks/CU on 160 KiB.
// ---------------------------------------------------------------------------
__global__ __launch_bounds__(256) void attn_kernel(
    const float* __restrict__ qb, const float* __restrict__ kb,
    const float* __restrict__ vb, float* __restrict__ ctxb)
{
    __shared__ float Qs[64][65];
    __shared__ float Ks[64][65];
    __shared__ float Vs[64][65];
    __shared__ float Ps[64][65];

    const int tid = threadIdx.x;
    const int tx  = tid & 15;
    const int ty  = tid >> 4;
    const int qt  = blockIdx.x;            // 0..15 q tiles
    const int bh  = blockIdx.y;            // 0..191 (b*NH + h)
    const int b   = bh / NH;
    const int h   = bh % NH;

    const int base = bh * SS * HDIM;       // start of this head's (S,HD) slab
    const float scale = 0.125f;            // HDIM^-0.5

    // Load Q tile (scale folded in): 64x64 floats, 4 float4 per thread
    #pragma unroll
    for (int l = 0; l < 4; ++l) {
        int f   = tid + l * 256;
        int row = f >> 4;                  // 16 float4 per row of 64
        int c4  = (f & 15) * 4;
        float4 v4 = *reinterpret_cast<const float4*>(
            &qb[base + (qt * 64 + row) * HDIM + c4]);
        Qs[row][c4 + 0] = v4.x * scale;
        Qs[row][c4 + 1] = v4.y * scale;
        Qs[row][c4 + 2] = v4.z * scale;
        Qs[row][c4 + 3] = v4.w * scale;
    }

    float m_r[4], l_r[4], ctx[4][4];
    #pragma unroll
    for (int i = 0; i < 4; ++i) {
        m_r[i] = -INFINITY;
        l_r[i] = 0.f;
        #pragma unroll
        for (int j = 0; j < 4; ++j) ctx[i][j] = 0.f;
    }

    for (int kt = 0; kt < 16; ++kt) {
        // Load K and V tiles (64x64 each)
        #pragma unroll
        for (int l = 0; l < 4; ++l) {
            int f   = tid + l * 256;
            int row = f >> 4;
            int c4  = (f & 15) * 4;
            int g   = base + (kt * 64 + row) * HDIM + c4;
            float4 kv = *reinterpret_cast<const float4*>(&kb[g]);
            Ks[row][c4 + 0] = kv.x; Ks[row][c4 + 1] = kv.y;
            Ks[row][c4 + 2] = kv.z; Ks[row][c4 + 3] = kv.w;
            float4 vv = *reinterpret_cast<const float4*>(&vb[g]);
            Vs[row][c4 + 0] = vv.x; Vs[row][c4 + 1] = vv.y;
            Vs[row][c4 + 2] = vv.z; Vs[row][c4 + 3] = vv.w;
        }
        __syncthreads();

        // Scores: 4x4 per thread, dot over hd
        float sc[4][4] = {};
        #pragma unroll
        for (int k = 0; k < 64; ++k) {
            float qv[4], kv[4];
            #pragma unroll
            for (int i = 0; i < 4; ++i) qv[i] = Qs[ty * 4 + i][k];
            #pragma unroll
            for (int j = 0; j < 4; ++j) kv[j] = Ks[tx * 4 + j][k];
            #pragma unroll
            for (int i = 0; i < 4; ++i)
                #pragma unroll
                for (int j = 0; j < 4; ++j)
                    sc[i][j] = fmaf(qv[i], kv[j], sc[i][j]);
        }

        // Online softmax update (reduce across the 16 lanes sharing ty)
        #pragma unroll
        for (int i = 0; i < 4; ++i) {
            float cm = fmaxf(fmaxf(sc[i][0], sc[i][1]),
                             fmaxf(sc[i][2], sc[i][3]));
            #pragma unroll
            for (int off = 1; off < 16; off <<= 1)
                cm = fmaxf(cm, __shfl_xor(cm, off, 64));
            float mnew  = fmaxf(m_r[i], cm);
            float corr  = __expf(m_r[i] - mnew);   // 0 on first tile (-inf)
            float rs = 0.f;
            #pragma unroll
            for (int j = 0; j < 4; ++j) {
                sc[i][j] = __expf(sc[i][j] - mnew);
                rs += sc[i][j];
            }
            #pragma unroll
            for (int off = 1; off < 16; off <<= 1)
                rs += __shfl_xor(rs, off, 64);
            l_r[i] = l_r[i] * corr + rs;
            m_r[i] = mnew;
            #pragma unroll
            for (int j = 0; j < 4; ++j) ctx[i][j] *= corr;
        }

        // Stage P, then PV accumulate
        #pragma unroll
        for (int i = 0; i < 4; ++i)
            #pragma unroll
            for (int j = 0; j < 4; ++j)
                Ps[ty * 4 + i][tx * 4 + j] = sc[i][j];
        __syncthreads();

        #pragma unroll
        for (int k = 0; k < 64; ++k) {
            float pv[4], vv[4];
            #pragma unroll
            for (int i = 0; i < 4; ++i) pv[i] = Ps[ty * 4 + i][k];
            #pragma unroll
            for (int j = 0; j < 4; ++j) vv[j] = Vs[k][tx * 4 + j];
            #pragma unroll
            for (int i = 0; i < 4; ++i)
                #pragma unroll
                for (int j = 0; j < 4; ++j)
                    ctx[i][j] = fmaf(pv[i], vv[j], ctx[i][j]);
        }
        __syncthreads();
    }

    // Epilogue: normalize and write ctx in (B,S,D) layout
    #pragma unroll
    for (int i = 0; i < 4; ++i) {
        float inv = 1.f / l_r[i];
        int srow = qt * 64 + ty * 4 + i;
        #pragma unroll
        for (int j = 0; j < 4; ++j) {
            int col = h * HDIM + tx * 4 + j;
            ctxb[(b * SS + srow) * DOUT + col] = ctx[i][j] * inv;
        }
    }
}

// ---------------------------------------------------------------------------
// Kernel 3: output projection GEMM + bias.  out[m][n] = ctx[m][:] @ wo + bo[n]
// Same tiling as kernel 1.
// ---------------------------------------------------------------------------
__global__ __launch_bounds__(256) void out_proj_kernel(
    const float* __restrict__ ctx, const float* __restrict__ wo,
    const float* __restrict__ bo, float* __restrict__ out)
{
    __shared__ float As[16][128 + 1];
    __shared__ float Bs[16][64 + 1];

    const int tx = threadIdx.x;
    const int ty = threadIdx.y;
    const int tid = ty * 16 + tx;

    const int m0 = blockIdx.x * 128;
    const int n0 = blockIdx.y * 64;

    float acc[8][4] = {};

    for (int k0 = 0; k0 < DOUT; k0 += 16) {
        #pragma unroll
        for (int l = 0; l < 2; ++l) {
            int f   = tid + l * 256;
            int row = f >> 2;
            int c4  = (f & 3) * 4;
            float4 av = *reinterpret_cast<const float4*>(
                &ctx[(m0 + row) * DOUT + k0 + c4]);
            As[c4 + 0][row] = av.x;
            As[c4 + 1][row] = av.y;
            As[c4 + 2][row] = av.z;
            As[c4 + 3][row] = av.w;
        }
        {
            int row = tid >> 4;
            int c4  = (tid & 15) * 4;
            float4 bv = *reinterpret_cast<const float4*>(
                &wo[(k0 + row) * DOUT + n0 + c4]);
            Bs[row][c4 + 0] = bv.x;
            Bs[row][c4 + 1] = bv.y;
            Bs[row][c4 + 2] = bv.z;
            Bs[row][c4 + 3] = bv.w;
        }
        __syncthreads();

        #pragma unroll
        for (int k = 0; k < 16; ++k) {
            float a[8], b[4];
            #pragma unroll
            for (int i = 0; i < 8; ++i) a[i] = As[k][ty * 8 + i];
            #pragma unroll
            for (int j = 0; j < 4; ++j) b[j] = Bs[k][tx * 4 + j];
            #pragma unroll
            for (int i = 0; i < 8; ++i)
                #pragma unroll
                for (int j = 0; j < 4; ++j)
                    acc[i][j] = fmaf(a[i], b[j], acc[i][j]);
        }
        __syncthreads();
    }

    #pragma unroll
    for (int i = 0; i < 8; ++i) {
        int m = m0 + ty * 8 + i;
        #pragma unroll
        for (int j = 0; j < 4; ++j) {
            int n = n0 + tx * 4 + j;
            out[m * DOUT + n] = acc[i][j] + bo[n];
        }
    }
}

// ---------------------------------------------------------------------------
extern "C" void kernel_launch(void* const* d_in, const int* in_sizes, int n_in,
                              void* d_out, int out_size, void* d_ws, size_t ws_size,
                              hipStream_t stream)
{
    const float* x  = (const float*)d_in[0];
    const float* wq = (const float*)d_in[1];
    const float* wk = (const float*)d_in[2];
    const float* wv = (const float*)d_in[3];
    const float* wo = (const float*)d_in[4];
    const float* bo = (const float*)d_in[5];
    float* out = (float*)d_out;

    // Workspace layout: Q, K, V in (B,H,S,HD); ctx in (B,S,D). 201 MB total.
    if (ws_size < (size_t)4 * BHSD * sizeof(float)) return;  // insufficient ws
    float* qb   = (float*)d_ws;
    float* kb   = qb + BHSD;
    float* vb   = kb + BHSD;
    float* ctxb = vb + BHSD;

    // K1: QKV projections. grid = (M/128, DOUT/64, 3)
    qkv_gemm_kernel<<<dim3(128, 12, 3), dim3(16, 16), 0, stream>>>(
        x, wq, wk, wv, qb, kb, vb);

    // K2: attention. grid = (S/64 q-tiles, B*NH heads)
    attn_kernel<<<dim3(16, 192), 256, 0, stream>>>(qb, kb, vb, ctxb);

    // K3: output projection. grid = (M/128, DOUT/64)
    out_proj_kernel<<<dim3(128, 12), dim3(16, 16), 0, stream>>>(
        ctxb, wo, bo, out);
}

// Round 3
// 400.972 us; speedup vs baseline: 6.1513x; 6.1513x over previous
//
#include <hip/hip_runtime.h>
#include <math.h>

// Problem constants
#define BB 16
#define SS 1024
#define DIN 768
#define DOUT 768
#define NH 12
#define HDIM 64
// M = BB*SS = 16384

typedef float  f32x4  __attribute__((ext_vector_type(4)));
typedef short  bf16x8 __attribute__((ext_vector_type(8)));
typedef unsigned short u16x4 __attribute__((ext_vector_type(4)));

// fp32 -> bf16 round-to-nearest-even
__device__ __forceinline__ unsigned short f2b(float f) {
    union { float f; unsigned u; } v; v.f = f;
    unsigned r = v.u + 0x7FFFu + ((v.u >> 16) & 1u);
    return (unsigned short)(r >> 16);
}

// ---------------------------------------------------------------------------
// K0a: x fp32 -> bf16
// ---------------------------------------------------------------------------
__global__ __launch_bounds__(256) void k_convert_x(
    const float* __restrict__ x, unsigned short* __restrict__ xb, int n4)
{
    for (int i = blockIdx.x * 256 + threadIdx.x; i < n4; i += gridDim.x * 256) {
        float4 v = reinterpret_cast<const float4*>(x)[i];
        u16x4 o;
        o[0] = f2b(v.x); o[1] = f2b(v.y); o[2] = f2b(v.z); o[3] = f2b(v.w);
        reinterpret_cast<u16x4*>(xb)[i] = o;
    }
}

// ---------------------------------------------------------------------------
// K0b: weight fp32 [k][n] -> bf16 transposed [n][k].  z: 0..2 -> wq/wk/wv into
// wt[z], z==3 -> wo into wot.  64x64 tiles via LDS.
// ---------------------------------------------------------------------------
__global__ __launch_bounds__(256) void k_convert_w(
    const float* __restrict__ wq, const float* __restrict__ wk,
    const float* __restrict__ wv, const float* __restrict__ wo,
    unsigned short* __restrict__ wt, unsigned short* __restrict__ wot)
{
    __shared__ float T[64][65];
    const int z = blockIdx.z;
    const float* in = (z == 0) ? wq : (z == 1) ? wk : (z == 2) ? wv : wo;
    unsigned short* out = (z < 3) ? (wt + z * DIN * DOUT) : wot;

    const int k0 = blockIdx.x * 64;
    const int n0 = blockIdx.y * 64;
    const int tid = threadIdx.x;

    for (int i = tid; i < 4096; i += 256) {
        int r = i >> 6, c = i & 63;
        T[r][c] = in[(k0 + r) * DOUT + n0 + c];
    }
    __syncthreads();
    for (int i = tid; i < 4096; i += 256) {
        int r = i >> 6, c = i & 63;           // r: n-local, c: k-local
        out[(n0 + r) * DIN + k0 + c] = f2b(T[c][r]);
    }
}

// ---------------------------------------------------------------------------
// K1: QKV GEMM, bf16 MFMA.  C = A(16384x768) * W(768x768), W given as Wt[n][k].
// BM=BN=128, BK=64, 256 threads = 4 waves (2x2), per-wave 64x64 via 4x4 frags
// of 16x16x32.  LDS tiles [128][64] bf16 with 16B-chunk XOR swizzle
// (chunk ^= row&7) on both write and read -> uniform bank use.
// Output written bf16 in (B,H,S,HD) layout; z selects q/k/v.
// ---------------------------------------------------------------------------
__global__ __launch_bounds__(256) void k_qkv_gemm(
    const unsigned short* __restrict__ A,   // xb [16384][768]
    const unsigned short* __restrict__ wt,  // [3][768][768] n-major
    unsigned short* __restrict__ qo, unsigned short* __restrict__ ko,
    unsigned short* __restrict__ vo)
{
    __shared__ unsigned short As[128 * 64];
    __shared__ unsigned short Bs[128 * 64];

    const int z = blockIdx.z;
    const unsigned short* Bt = wt + z * DIN * DOUT;
    unsigned short* outb = (z == 0) ? qo : (z == 1) ? ko : vo;

    const int tid  = threadIdx.x;
    const int lane = tid & 63;
    const int wid  = tid >> 6;
    const int wm   = wid >> 1, wn = wid & 1;
    const int lr   = lane & 15, lg = lane >> 4;

    const int m0 = blockIdx.x * 128;
    const int n0 = blockIdx.y * 128;

    f32x4 acc[4][4];
    #pragma unroll
    for (int i = 0; i < 4; ++i)
        #pragma unroll
        for (int j = 0; j < 4; ++j) acc[i][j] = (f32x4){0.f, 0.f, 0.f, 0.f};

    for (int kt = 0; kt < DIN / 64; ++kt) {
        const int k0 = kt * 64;
        #pragma unroll
        for (int t = 0; t < 4; ++t) {
            int c = tid + t * 256;          // 0..1023 chunks of 8 bf16
            int r = c >> 3, ch = c & 7;
            *reinterpret_cast<bf16x8*>(&As[(r << 6) + ((ch ^ (r & 7)) << 3)]) =
                *reinterpret_cast<const bf16x8*>(&A[(m0 + r) * DIN + k0 + (ch << 3)]);
            *reinterpret_cast<bf16x8*>(&Bs[(r << 6) + ((ch ^ (r & 7)) << 3)]) =
                *reinterpret_cast<const bf16x8*>(&Bt[(n0 + r) * DIN + k0 + (ch << 3)]);
        }
        __syncthreads();

        #pragma unroll
        for (int ks = 0; ks < 2; ++ks) {
            bf16x8 af[4], bfr[4];
            #pragma unroll
            for (int mi = 0; mi < 4; ++mi) {
                int r = wm * 64 + mi * 16 + lr;
                af[mi] = *reinterpret_cast<const bf16x8*>(
                    &As[(r << 6) + ((((ks << 2) + lg) ^ (r & 7)) << 3)]);
            }
            #pragma unroll
            for (int ni = 0; ni < 4; ++ni) {
                int r = wn * 64 + ni * 16 + lr;
                bfr[ni] = *reinterpret_cast<const bf16x8*>(
                    &Bs[(r << 6) + ((((ks << 2) + lg) ^ (r & 7)) << 3)]);
            }
            #pragma unroll
            for (int mi = 0; mi < 4; ++mi)
                #pragma unroll
                for (int ni = 0; ni < 4; ++ni)
                    acc[mi][ni] = __builtin_amdgcn_mfma_f32_16x16x32_bf16(
                        af[mi], bfr[ni], acc[mi][ni], 0, 0, 0);
        }
        __syncthreads();
    }

    // Epilogue: C/D map col=lane&15, row=(lane>>4)*4+reg.  Write (B,H,S,HD).
    #pragma unroll
    for (int mi = 0; mi < 4; ++mi) {
        #pragma unroll
        for (int rg = 0; rg < 4; ++rg) {
            int m = m0 + wm * 64 + mi * 16 + lg * 4 + rg;
            int b = m >> 10, s = m & 1023;
            #pragma unroll
            for (int ni = 0; ni < 4; ++ni) {
                int n = n0 + wn * 64 + ni * 16 + lr;
                int h = n >> 6, hd = n & 63;
                outb[((b * NH + h) * SS + s) * HDIM + hd] = f2b(acc[mi][ni][rg]);
            }
        }
    }
}

// ---------------------------------------------------------------------------
// K1b: transpose V: (B,H,S,HD) bf16 -> (B,H,HD,S) bf16.  64x64 tiles.
// ---------------------------------------------------------------------------
__global__ __launch_bounds__(256) void k_vtrans(
    const unsigned short* __restrict__ vb, unsigned short* __restrict__ vt)
{
    __shared__ unsigned short T[64 * 72];   // 144B rows, 16B aligned
    const int tid = threadIdx.x;
    const int st  = blockIdx.x;             // s-tile 0..15
    const int bh  = blockIdx.y;             // 0..191
    const int base = bh << 16;              // bh * 1024 * 64

    #pragma unroll
    for (int t = 0; t < 2; ++t) {
        int c = tid + t * 256;              // 512 chunks
        int s = c >> 3, d0 = (c & 7) << 3;
        *reinterpret_cast<bf16x8*>(&T[s * 72 + d0]) =
            *reinterpret_cast<const bf16x8*>(&vb[base + ((st * 64 + s) << 6) + d0]);
    }
    __syncthreads();
    #pragma unroll
    for (int t = 0; t < 2; ++t) {
        int c = tid + t * 256;
        int d = c >> 3, s0 = (c & 7) << 3;
        bf16x8 o;
        #pragma unroll
        for (int i = 0; i < 8; ++i) o[i] = (short)T[(s0 + i) * 72 + d];
        *reinterpret_cast<bf16x8*>(&vt[base + (d << 10) + st * 64 + s0]) = o;
    }
}

// ---------------------------------------------------------------------------
// K2: flash attention, bf16 MFMA.  Block = (qt, bh); 4 waves; wave w owns
// q-rows [w*16, w*16+16).  Per kv-tile (64 keys): QK^T (8 MFMA) -> fp32
// online softmax (shfl over the 16 lanes sharing lg) -> P bf16 to LDS
// (own rows only, no barrier) -> PV (8 MFMA).  V consumed from the
// pre-transposed (B,H,HD,S) buffer so B-frags are contiguous.
// ---------------------------------------------------------------------------
__global__ __launch_bounds__(256) void k_attn(
    const unsigned short* __restrict__ qb, const unsigned short* __restrict__ kb,
    const unsigned short* __restrict__ vt, unsigned short* __restrict__ ctxb)
{
    __shared__ unsigned short Qs[64 * 64];
    __shared__ unsigned short Ks[64 * 64];
    __shared__ unsigned short Vs[64 * 64];   // holds V^T tile: rows=d, cols=key
    __shared__ unsigned short Ps[64 * 64];

    const int tid  = threadIdx.x;
    const int lane = tid & 63;
    const int w    = tid >> 6;
    const int lr   = lane & 15, lg = lane >> 4;
    const int qt   = blockIdx.x;
    const int bh   = blockIdx.y;
    const int b    = bh / NH, h = bh % NH;
    const int base = bh << 16;               // bh * 1024 * 64

    // Stage Q tile (rows = q-local)
    #pragma unroll
    for (int t = 0; t < 2; ++t) {
        int c = tid + t * 256;
        int r = c >> 3, ch = c & 7;
        *reinterpret_cast<bf16x8*>(&Qs[(r << 6) + ((ch ^ (r & 7)) << 3)]) =
            *reinterpret_cast<const bf16x8*>(&qb[base + ((qt * 64 + r) << 6) + (ch << 3)]);
    }

    float m_r[4], l_r[4];
    f32x4 ctx[4];
    #pragma unroll
    for (int i = 0; i < 4; ++i) {
        m_r[i] = -INFINITY; l_r[i] = 0.f;
        ctx[i] = (f32x4){0.f, 0.f, 0.f, 0.f};
    }

    for (int kt = 0; kt < 16; ++kt) {
        #pragma unroll
        for (int t = 0; t < 2; ++t) {
            int c = tid + t * 256;
            int r = c >> 3, ch = c & 7;
            *reinterpret_cast<bf16x8*>(&Ks[(r << 6) + ((ch ^ (r & 7)) << 3)]) =
                *reinterpret_cast<const bf16x8*>(&kb[base + ((kt * 64 + r) << 6) + (ch << 3)]);
            *reinterpret_cast<bf16x8*>(&Vs[(r << 6) + ((ch ^ (r & 7)) << 3)]) =
                *reinterpret_cast<const bf16x8*>(&vt[base + (r << 10) + (kt << 6) + (ch << 3)]);
        }
        __syncthreads();   // covers Q on first iter too

        // QK^T: S[q][key], q = w*16 + (C-row), key = ni*16 + (C-col)
        f32x4 sc[4];
        #pragma unroll
        for (int ni = 0; ni < 4; ++ni) sc[ni] = (f32x4){0.f, 0.f, 0.f, 0.f};
        #pragma unroll
        for (int ks = 0; ks < 2; ++ks) {
            int qrow = (w << 4) + lr;
            bf16x8 aq = *reinterpret_cast<const bf16x8*>(
                &Qs[(qrow << 6) + ((((ks << 2) + lg) ^ (qrow & 7)) << 3)]);
            #pragma unroll
            for (int ni = 0; ni < 4; ++ni) {
                int krow = (ni << 4) + lr;
                bf16x8 bk = *reinterpret_cast<const bf16x8*>(
                    &Ks[(krow << 6) + ((((ks << 2) + lg) ^ (krow & 7)) << 3)]);
                sc[ni] = __builtin_amdgcn_mfma_f32_16x16x32_bf16(aq, bk, sc[ni], 0, 0, 0);
            }
        }
        #pragma unroll
        for (int ni = 0; ni < 4; ++ni) sc[ni] *= 0.125f;   // HD^-0.5

        // Online softmax per q-row (row = lg*4+rg; 16 lanes sharing lg hold keys)
        #pragma unroll
        for (int rg = 0; rg < 4; ++rg) {
            float mx = fmaxf(fmaxf(sc[0][rg], sc[1][rg]),
                             fmaxf(sc[2][rg], sc[3][rg]));
            #pragma unroll
            for (int o = 1; o < 16; o <<= 1) mx = fmaxf(mx, __shfl_xor(mx, o));
            float mnew = fmaxf(m_r[rg], mx);
            float corr = __expf(m_r[rg] - mnew);
            float rs = 0.f;
            #pragma unroll
            for (int ni = 0; ni < 4; ++ni) {
                float p = __expf(sc[ni][rg] - mnew);
                sc[ni][rg] = p; rs += p;
            }
            #pragma unroll
            for (int o = 1; o < 16; o <<= 1) rs += __shfl_xor(rs, o);
            l_r[rg] = l_r[rg] * corr + rs;
            m_r[rg] = mnew;
            #pragma unroll
            for (int di = 0; di < 4; ++di) ctx[di][rg] *= corr;
        }

        // P -> LDS bf16 (this wave's own 16 rows; no barrier needed before PV)
        #pragma unroll
        for (int rg = 0; rg < 4; ++rg) {
            int qr = (w << 4) + (lg << 2) + rg;
            #pragma unroll
            for (int ni = 0; ni < 4; ++ni) {
                int key = (ni << 4) + lr;
                Ps[(qr << 6) + ((((key >> 3) ^ (qr & 7)) << 3)) + (key & 7)]
                    = f2b(sc[ni][rg]);
            }
        }

        // PV: ctx[q][d] += P[q][key] * V[key][d];  B-frag from V^T rows (=d)
        #pragma unroll
        for (int ks = 0; ks < 2; ++ks) {
            int prow = (w << 4) + lr;
            bf16x8 ap = *reinterpret_cast<const bf16x8*>(
                &Ps[(prow << 6) + ((((ks << 2) + lg) ^ (prow & 7)) << 3)]);
            #pragma unroll
            for (int di = 0; di < 4; ++di) {
                int vrow = (di << 4) + lr;
                bf16x8 bv = *reinterpret_cast<const bf16x8*>(
                    &Vs[(vrow << 6) + ((((ks << 2) + lg) ^ (vrow & 7)) << 3)]);
                ctx[di] = __builtin_amdgcn_mfma_f32_16x16x32_bf16(ap, bv, ctx[di], 0, 0, 0);
            }
        }
        __syncthreads();   // before re-staging K/V
    }

    // Epilogue: normalize, write ctx bf16 (B,S,D)
    #pragma unroll
    for (int rg = 0; rg < 4; ++rg) {
        float inv = 1.f / l_r[rg];
        int q = (qt << 6) + (w << 4) + (lg << 2) + rg;
        #pragma unroll
        for (int di = 0; di < 4; ++di) {
            int d = (di << 4) + lr;
            ctxb[(b * SS + q) * DOUT + h * HDIM + d] = f2b(ctx[di][rg] * inv);
        }
    }
}

// ---------------------------------------------------------------------------
// K3: output projection, bf16 MFMA + fp32 bias, fp32 out.  Same core as K1.
// ---------------------------------------------------------------------------
__global__ __launch_bounds__(256) void k_out_gemm(
    const unsigned short* __restrict__ A,    // ctxb [16384][768] bf16
    const unsigned short* __restrict__ Bt,   // wot [768][768] n-major bf16
    const float* __restrict__ bo, float* __restrict__ out)
{
    __shared__ unsigned short As[128 * 64];
    __shared__ unsigned short Bs[128 * 64];

    const int tid  = threadIdx.x;
    const int lane = tid & 63;
    const int wid  = tid >> 6;
    const int wm   = wid >> 1, wn = wid & 1;
    const int lr   = lane & 15, lg = lane >> 4;

    const int m0 = blockIdx.x * 128;
    const int n0 = blockIdx.y * 128;

    f32x4 acc[4][4];
    #pragma unroll
    for (int i = 0; i < 4; ++i)
        #pragma unroll
        for (int j = 0; j < 4; ++j) acc[i][j] = (f32x4){0.f, 0.f, 0.f, 0.f};

    for (int kt = 0; kt < DOUT / 64; ++kt) {
        const int k0 = kt * 64;
        #pragma unroll
        for (int t = 0; t < 4; ++t) {
            int c = tid + t * 256;
            int r = c >> 3, ch = c & 7;
            *reinterpret_cast<bf16x8*>(&As[(r << 6) + ((ch ^ (r & 7)) << 3)]) =
                *reinterpret_cast<const bf16x8*>(&A[(m0 + r) * DOUT + k0 + (ch << 3)]);
            *reinterpret_cast<bf16x8*>(&Bs[(r << 6) + ((ch ^ (r & 7)) << 3)]) =
                *reinterpret_cast<const bf16x8*>(&Bt[(n0 + r) * DOUT + k0 + (ch << 3)]);
        }
        __syncthreads();

        #pragma unroll
        for (int ks = 0; ks < 2; ++ks) {
            bf16x8 af[4], bfr[4];
            #pragma unroll
            for (int mi = 0; mi < 4; ++mi) {
                int r = wm * 64 + mi * 16 + lr;
                af[mi] = *reinterpret_cast<const bf16x8*>(
                    &As[(r << 6) + ((((ks << 2) + lg) ^ (r & 7)) << 3)]);
            }
            #pragma unroll
            for (int ni = 0; ni < 4; ++ni) {
                int r = wn * 64 + ni * 16 + lr;
                bfr[ni] = *reinterpret_cast<const bf16x8*>(
                    &Bs[(r << 6) + ((((ks << 2) + lg) ^ (r & 7)) << 3)]);
            }
            #pragma unroll
            for (int mi = 0; mi < 4; ++mi)
                #pragma unroll
                for (int ni = 0; ni < 4; ++ni)
                    acc[mi][ni] = __builtin_amdgcn_mfma_f32_16x16x32_bf16(
                        af[mi], bfr[ni], acc[mi][ni], 0, 0, 0);
        }
        __syncthreads();
    }

    #pragma unroll
    for (int mi = 0; mi < 4; ++mi) {
        #pragma unroll
        for (int rg = 0; rg < 4; ++rg) {
            int m = m0 + wm * 64 + mi * 16 + lg * 4 + rg;
            #pragma unroll
            for (int ni = 0; ni < 4; ++ni) {
                int n = n0 + wn * 64 + ni * 16 + lr;
                out[m * DOUT + n] = acc[mi][ni][rg] + bo[n];
            }
        }
    }
}

// ---------------------------------------------------------------------------
extern "C" void kernel_launch(void* const* d_in, const int* in_sizes, int n_in,
                              void* d_out, int out_size, void* d_ws, size_t ws_size,
                              hipStream_t stream)
{
    const float* x  = (const float*)d_in[0];
    const float* wq = (const float*)d_in[1];
    const float* wk = (const float*)d_in[2];
    const float* wv = (const float*)d_in[3];
    const float* wo = (const float*)d_in[4];
    const float* bo = (const float*)d_in[5];
    float* out = (float*)d_out;

    // Workspace layout (bf16 = ushort elements):
    const size_t N_X   = (size_t)BB * SS * DIN;      // 12,582,912
    const size_t N_W   = (size_t)DIN * DOUT;         // 589,824
    const size_t N_BHSD= (size_t)BB * NH * SS * HDIM;// 12,582,912

    unsigned short* xb   = (unsigned short*)d_ws;
    unsigned short* wt   = xb   + N_X;        // [3][768][768] transposed
    unsigned short* wot  = wt   + 3 * N_W;
    unsigned short* qbuf = wot  + N_W;
    unsigned short* kbuf = qbuf + N_BHSD;
    unsigned short* vbuf = kbuf + N_BHSD;
    unsigned short* vtb  = vbuf + N_BHSD;     // V transposed (B,H,HD,S)
    unsigned short* ctxb = vtb  + N_BHSD;

    size_t need = (N_X + 4 * N_W + 5 * N_BHSD) * sizeof(unsigned short);
    if (ws_size < need) return;

    // K0a: x -> bf16
    k_convert_x<<<4096, 256, 0, stream>>>(x, xb, (int)(N_X / 4));
    // K0b: weights -> bf16 transposed
    k_convert_w<<<dim3(12, 12, 4), 256, 0, stream>>>(wq, wk, wv, wo, wt, wot);
    // K1: QKV projections
    k_qkv_gemm<<<dim3(128, 6, 3), 256, 0, stream>>>(xb, wt, qbuf, kbuf, vbuf);
    // K1b: V transpose
    k_vtrans<<<dim3(16, 192), 256, 0, stream>>>(vbuf, vtb);
    // K2: attention
    k_attn<<<dim3(16, 192), 256, 0, stream>>>(qbuf, kbuf, vtb, ctxb);
    // K3: output projection
    k_out_gemm<<<dim3(128, 6), 256, 0, stream>>>(ctxb, wot, bo, out);
}

// Round 6
// 354.958 us; speedup vs baseline: 6.9487x; 1.1296x over previous
//
#include <hip/hip_runtime.h>
#include <math.h>

#define BB 16
#define SS 1024
#define DIN 768
#define DOUT 768
#define NH 12
#define HDIM 64

typedef float  f32x4   __attribute__((ext_vector_type(4)));
typedef float  f32x16  __attribute__((ext_vector_type(16)));
typedef short  bf16x8  __attribute__((ext_vector_type(8)));
typedef unsigned short u16x4 __attribute__((ext_vector_type(4)));

// fp32 -> bf16 round-to-nearest-even
__device__ __forceinline__ unsigned short f2b(float f) {
    union { float f; unsigned u; } v; v.f = f;
    unsigned r = v.u + 0x7FFFu + ((v.u >> 16) & 1u);
    return (unsigned short)(r >> 16);
}

// global -> LDS direct (16B/lane). LDS dest must be wave-uniform base; HW
// writes base + lane*16. Swizzle achieved by inverse-permuted global source.
#define GLOAD16(gp, lp) __builtin_amdgcn_global_load_lds( \
    (const __attribute__((address_space(1))) void*)(gp),  \
    (__attribute__((address_space(3))) void*)(lp), 16, 0, 0)

// ---------------------------------------------------------------------------
// K0a: x fp32 -> bf16
// ---------------------------------------------------------------------------
__global__ __launch_bounds__(256) void k_convert_x(
    const float* __restrict__ x, unsigned short* __restrict__ xb, int n4)
{
    for (int i = blockIdx.x * 256 + threadIdx.x; i < n4; i += gridDim.x * 256) {
        float4 v = reinterpret_cast<const float4*>(x)[i];
        u16x4 o;
        o[0] = f2b(v.x); o[1] = f2b(v.y); o[2] = f2b(v.z); o[3] = f2b(v.w);
        reinterpret_cast<u16x4*>(xb)[i] = o;
    }
}

// ---------------------------------------------------------------------------
// K0b: weight fp32 [k][n] -> bf16 transposed [n][k]. z 0..2 -> wq/wk/wv, 3 -> wo.
// ---------------------------------------------------------------------------
__global__ __launch_bounds__(256) void k_convert_w(
    const float* __restrict__ wq, const float* __restrict__ wk,
    const float* __restrict__ wv, const float* __restrict__ wo,
    unsigned short* __restrict__ wt, unsigned short* __restrict__ wot)
{
    __shared__ float T[64][65];
    const int z = blockIdx.z;
    const float* in = (z == 0) ? wq : (z == 1) ? wk : (z == 2) ? wv : wo;
    unsigned short* out = (z < 3) ? (wt + (size_t)z * DIN * DOUT) : wot;

    const int k0 = blockIdx.x * 64;
    const int n0 = blockIdx.y * 64;
    const int tid = threadIdx.x;

    for (int i = tid; i < 4096; i += 256) {
        int r = i >> 6, c = i & 63;
        T[r][c] = in[(k0 + r) * DOUT + n0 + c];
    }
    __syncthreads();
    for (int i = tid; i < 4096; i += 256) {
        int r = i >> 6, c = i & 63;
        out[(size_t)(n0 + r) * DIN + k0 + c] = f2b(T[c][r]);
    }
}

// ---------------------------------------------------------------------------
// K1: QKV GEMM, bf16 MFMA 16x16x32.  BM=BN=128, BK=64, 4 waves (2x2).
// Staging: global_load_lds dwordx4, LDS linear, source pre-swizzled so that
// linear LDS (r, ch) holds global chunk (r, ch^(r&7)); reads apply the XOR.
// z==0: Q scaled by HD^-0.5 at write.  z==2: V written TRANSPOSED (B,H,HD,S).
// ---------------------------------------------------------------------------
__global__ __launch_bounds__(256) void k_qkv_gemm(
    const unsigned short* __restrict__ A,   // xb [16384][768]
    const unsigned short* __restrict__ wt,  // [3][768 n][768 k]
    unsigned short* __restrict__ qo, unsigned short* __restrict__ ko,
    unsigned short* __restrict__ vtb)       // V^T (B,H,HD,S)
{
    __shared__ unsigned short As[128 * 64];
    __shared__ unsigned short Bs[128 * 64];

    const int z = blockIdx.z;
    const unsigned short* Bt = wt + (size_t)z * DIN * DOUT;

    const int tid  = threadIdx.x;
    const int lane = tid & 63;
    const int wid  = tid >> 6;
    const int wm   = wid >> 1, wn = wid & 1;
    const int lr   = lane & 15, lg = lane >> 4;

    const int m0 = blockIdx.x * 128;
    const int n0 = blockIdx.y * 128;

    f32x4 acc[4][4];
    #pragma unroll
    for (int i = 0; i < 4; ++i)
        #pragma unroll
        for (int j = 0; j < 4; ++j) acc[i][j] = (f32x4){0.f, 0.f, 0.f, 0.f};

    for (int kt = 0; kt < DIN / 64; ++kt) {
        const int k0 = kt * 64;
        #pragma unroll
        for (int t = 0; t < 4; ++t) {
            int c  = t * 256 + wid * 64 + lane;   // linear 16B-chunk id
            int r  = c >> 3;
            int ch = (c & 7) ^ (r & 7);           // inverse-swizzled source
            GLOAD16(&A[(size_t)(m0 + r) * DIN + k0 + (ch << 3)],
                    &As[(t * 256 + wid * 64) * 8]);
            GLOAD16(&Bt[(size_t)(n0 + r) * DIN + k0 + (ch << 3)],
                    &Bs[(t * 256 + wid * 64) * 8]);
        }
        __syncthreads();   // drains vmcnt (compiler-inserted)

        #pragma unroll
        for (int ks = 0; ks < 2; ++ks) {
            bf16x8 af[4], bfr[4];
            #pragma unroll
            for (int mi = 0; mi < 4; ++mi) {
                int r = wm * 64 + mi * 16 + lr;
                af[mi] = *reinterpret_cast<const bf16x8*>(
                    &As[(r << 6) + ((((ks << 2) + lg) ^ (r & 7)) << 3)]);
            }
            #pragma unroll
            for (int ni = 0; ni < 4; ++ni) {
                int r = wn * 64 + ni * 16 + lr;
                bfr[ni] = *reinterpret_cast<const bf16x8*>(
                    &Bs[(r << 6) + ((((ks << 2) + lg) ^ (r & 7)) << 3)]);
            }
            #pragma unroll
            for (int mi = 0; mi < 4; ++mi)
                #pragma unroll
                for (int ni = 0; ni < 4; ++ni)
                    acc[mi][ni] = __builtin_amdgcn_mfma_f32_16x16x32_bf16(
                        af[mi], bfr[ni], acc[mi][ni], 0, 0, 0);
        }
        __syncthreads();
    }

    const float oscale = (z == 0) ? 0.125f : 1.0f;   // fold HD^-0.5 into Q
    #pragma unroll
    for (int mi = 0; mi < 4; ++mi) {
        #pragma unroll
        for (int rg = 0; rg < 4; ++rg) {
            int m = m0 + wm * 64 + mi * 16 + lg * 4 + rg;
            int b = m >> 10, s = m & 1023;
            #pragma unroll
            for (int ni = 0; ni < 4; ++ni) {
                int n = n0 + wn * 64 + ni * 16 + lr;
                int h = n >> 6, hd = n & 63;
                unsigned short val = f2b(acc[mi][ni][rg] * oscale);
                if (z == 2) {
                    // V^T: (B,H,HD,S)
                    vtb[(((size_t)(b * NH + h)) << 16) + (hd << 10) + s] = val;
                } else {
                    unsigned short* ob = (z == 0) ? qo : ko;
                    ob[(((size_t)(b * NH + h) * SS + s) << 6) + hd] = val;
                }
            }
        }
    }
}

// ---------------------------------------------------------------------------
// K2: flash attention, 32x32x16 bf16 MFMA, swapped operands.
// Block = (qt 0..7, bh 0..191), 4 waves, wave owns 32 q-rows (QBLK=128).
// Per kv-tile (64 keys):
//   QK^T = mfma(K, Q): C[key][q]; lane holds q=lane&31, keys crow(r,h)+32b,
//     crow(r,h) = (r&3)+8*(r>>2)+4h, h = lane>>5.
//   Softmax fully in-register: partner lanes (l, l^32) jointly hold 64 keys.
//   P -> bf16 pairs pk_b[j] = keys 32b+8(j>>1)+4h'+2(j&1)+{0,1} (h'=holder half).
//   PV B-frag u[t] at MFMA kk, lane h needs keys 16kk+8h+2t+{0,1}
//     -> b=(kk>=2), h_src=t>>1, j=4(kk&1)+2h+(t&1)  [verified, all 8 cases].
//   PV = mfma(V^T, P): C[d][q] -> rescale factor stays lane-local.
// ---------------------------------------------------------------------------
__global__ __launch_bounds__(256) void k_attn(
    const unsigned short* __restrict__ qb, const unsigned short* __restrict__ kb,
    const unsigned short* __restrict__ vt, unsigned short* __restrict__ ctxb)
{
    __shared__ unsigned short Ks[64 * 64];   // [key][hd], source-swizzled
    __shared__ unsigned short Vs[64 * 64];   // [d][s],   source-swizzled

    const int tid  = threadIdx.x;
    const int lane = tid & 63;
    const int w    = tid >> 6;
    const int h    = lane >> 5;
    const int q31  = lane & 31;
    const int qt   = blockIdx.x;
    const int bh   = blockIdx.y;
    const int bb   = bh / NH, hh = bh % NH;
    const size_t base = (size_t)bh << 16;

    const int q_glob = qt * 128 + w * 32 + q31;

    // Q B-frags in registers: qf[kk] covers k = 16kk + 8h + 0..7 (Q pre-scaled)
    bf16x8 qf[4];
    #pragma unroll
    for (int kk = 0; kk < 4; ++kk)
        qf[kk] = *reinterpret_cast<const bf16x8*>(
            &qb[base + ((size_t)q_glob << 6) + (kk << 4) + (h << 3)]);

    float m_run = -INFINITY, l_run = 0.f;
    f32x16 ctx0, ctx1;
    #pragma unroll
    for (int i = 0; i < 16; ++i) { ctx0[i] = 0.f; ctx1[i] = 0.f; }

    for (int kt = 0; kt < 16; ++kt) {
        // ---- stage K tile and V^T tile (swizzle-by-source) ----
        #pragma unroll
        for (int t = 0; t < 2; ++t) {
            int c  = t * 256 + w * 64 + lane;
            int r  = c >> 3;
            int ch = (c & 7) ^ (r & 7);
            GLOAD16(&kb[base + ((size_t)(kt * 64 + r) << 6) + (ch << 3)],
                    &Ks[(t * 256 + w * 64) * 8]);
            GLOAD16(&vt[base + ((size_t)r << 10) + (kt << 6) + (ch << 3)],
                    &Vs[(t * 256 + w * 64) * 8]);
        }
        __syncthreads();

        // ---- QK^T (swapped): sc0 = keys 0..31, sc1 = keys 32..63 ----
        f32x16 sc0, sc1;
        #pragma unroll
        for (int i = 0; i < 16; ++i) { sc0[i] = 0.f; sc1[i] = 0.f; }
        #pragma unroll
        for (int kk = 0; kk < 4; ++kk) {
            int ch = (kk << 1) + h;              // hd chunk for this k-step
            int r0 = q31, r1 = q31 + 32;         // key rows (A-frag row=lane&31)
            bf16x8 kf0 = *reinterpret_cast<const bf16x8*>(
                &Ks[(r0 << 6) + ((ch ^ (r0 & 7)) << 3)]);
            bf16x8 kf1 = *reinterpret_cast<const bf16x8*>(
                &Ks[(r1 << 6) + ((ch ^ (r1 & 7)) << 3)]);
            sc0 = __builtin_amdgcn_mfma_f32_32x32x16_bf16(kf0, qf[kk], sc0, 0, 0, 0);
            sc1 = __builtin_amdgcn_mfma_f32_32x32x16_bf16(kf1, qf[kk], sc1, 0, 0, 0);
        }

        // ---- in-register online softmax (one q per lane-pair) ----
        float mx = fmaxf(sc0[0], sc1[0]);
        #pragma unroll
        for (int i = 1; i < 16; ++i) mx = fmaxf(mx, fmaxf(sc0[i], sc1[i]));
        mx = fmaxf(mx, __shfl_xor(mx, 32));
        float mnew = fmaxf(m_run, mx);
        float corr = __expf(m_run - mnew);
        float p0[16], p1[16];
        float rs = 0.f;
        #pragma unroll
        for (int i = 0; i < 16; ++i) {
            p0[i] = __expf(sc0[i] - mnew); rs += p0[i];
            p1[i] = __expf(sc1[i] - mnew); rs += p1[i];
        }
        rs += __shfl_xor(rs, 32);
        l_run = l_run * corr + rs;
        m_run = mnew;
        #pragma unroll
        for (int i = 0; i < 16; ++i) { ctx0[i] *= corr; ctx1[i] *= corr; }

        // ---- pack P to bf16 pairs ----
        unsigned pk0[8], pk1[8];
        #pragma unroll
        for (int j = 0; j < 8; ++j) {
            pk0[j] = (unsigned)f2b(p0[2 * j]) | ((unsigned)f2b(p0[2 * j + 1]) << 16);
            pk1[j] = (unsigned)f2b(p1[2 * j]) | ((unsigned)f2b(p1[2 * j + 1]) << 16);
        }

        // ---- redistribute + PV ----
        #pragma unroll
        for (int kk = 0; kk < 4; ++kk) {
            unsigned a0, a1, b0, b1;
            if (kk < 2) {
                a0 = pk0[4 * (kk & 1)];     a1 = pk0[4 * (kk & 1) + 1];
                b0 = pk0[4 * (kk & 1) + 2]; b1 = pk0[4 * (kk & 1) + 3];
            } else {
                a0 = pk1[4 * (kk & 1)];     a1 = pk1[4 * (kk & 1) + 1];
                b0 = pk1[4 * (kk & 1) + 2]; b1 = pk1[4 * (kk & 1) + 3];
            }
            unsigned mine0 = h ? b0 : a0, mine1 = h ? b1 : a1;   // my-index, my half
            unsigned give0 = h ? a0 : b0, give1 = h ? a1 : b1;   // partner's index
            unsigned sw0 = (unsigned)__shfl_xor((int)give0, 32);
            unsigned sw1 = (unsigned)__shfl_xor((int)give1, 32);
            union { unsigned u[4]; bf16x8 v; } pf;
            pf.u[0] = h ? sw0 : mine0;     // t=0 (h_src=0)
            pf.u[1] = h ? sw1 : mine1;     // t=1 (h_src=0)
            pf.u[2] = h ? mine0 : sw0;     // t=2 (h_src=1)
            pf.u[3] = h ? mine1 : sw1;     // t=3 (h_src=1)

            int ch = (kk << 1) + h;        // key chunk for this k-step
            int d0 = q31, d1 = q31 + 32;   // V^T rows = d
            bf16x8 vf0 = *reinterpret_cast<const bf16x8*>(
                &Vs[(d0 << 6) + ((ch ^ (d0 & 7)) << 3)]);
            bf16x8 vf1 = *reinterpret_cast<const bf16x8*>(
                &Vs[(d1 << 6) + ((ch ^ (d1 & 7)) << 3)]);
            ctx0 = __builtin_amdgcn_mfma_f32_32x32x16_bf16(vf0, pf.v, ctx0, 0, 0, 0);
            ctx1 = __builtin_amdgcn_mfma_f32_32x32x16_bf16(vf1, pf.v, ctx1, 0, 0, 0);
        }
        __syncthreads();
    }

    // ---- epilogue: normalize, write ctx bf16 (B,S,D) ----
    float inv = 1.f / l_run;
    size_t obase = ((size_t)(bb * SS + q_glob)) * DOUT + hh * HDIM;
    #pragma unroll
    for (int g = 0; g < 4; ++g) {          // d rows: 8g + 4h + {0..3} (+32)
        u16x4 o0, o1;
        #pragma unroll
        for (int e = 0; e < 4; ++e) {
            o0[e] = f2b(ctx0[4 * g + e] * inv);
            o1[e] = f2b(ctx1[4 * g + e] * inv);
        }
        *reinterpret_cast<u16x4*>(&ctxb[obase + 8 * g + 4 * h])      = o0;
        *reinterpret_cast<u16x4*>(&ctxb[obase + 8 * g + 4 * h + 32]) = o1;
    }
}

// ---------------------------------------------------------------------------
// K3: output projection, bf16 MFMA + fp32 bias, fp32 out. Same core as K1.
// ---------------------------------------------------------------------------
__global__ __launch_bounds__(256) void k_out_gemm(
    const unsigned short* __restrict__ A,    // ctxb [16384][768] bf16
    const unsigned short* __restrict__ Bt,   // wot [768 n][768 k] bf16
    const float* __restrict__ bo, float* __restrict__ out)
{
    __shared__ unsigned short As[128 * 64];
    __shared__ unsigned short Bs[128 * 64];

    const int tid  = threadIdx.x;
    const int lane = tid & 63;
    const int wid  = tid >> 6;
    const int wm   = wid >> 1, wn = wid & 1;
    const int lr   = lane & 15, lg = lane >> 4;

    const int m0 = blockIdx.x * 128;
    const int n0 = blockIdx.y * 128;

    f32x4 acc[4][4];
    #pragma unroll
    for (int i = 0; i < 4; ++i)
        #pragma unroll
        for (int j = 0; j < 4; ++j) acc[i][j] = (f32x4){0.f, 0.f, 0.f, 0.f};

    for (int kt = 0; kt < DOUT / 64; ++kt) {
        const int k0 = kt * 64;
        #pragma unroll
        for (int t = 0; t < 4; ++t) {
            int c  = t * 256 + wid * 64 + lane;
            int r  = c >> 3;
            int ch = (c & 7) ^ (r & 7);
            GLOAD16(&A[(size_t)(m0 + r) * DOUT + k0 + (ch << 3)],
                    &As[(t * 256 + wid * 64) * 8]);
            GLOAD16(&Bt[(size_t)(n0 + r) * DOUT + k0 + (ch << 3)],
                    &Bs[(t * 256 + wid * 64) * 8]);
        }
        __syncthreads();

        #pragma unroll
        for (int ks = 0; ks < 2; ++ks) {
            bf16x8 af[4], bfr[4];
            #pragma unroll
            for (int mi = 0; mi < 4; ++mi) {
                int r = wm * 64 + mi * 16 + lr;
                af[mi] = *reinterpret_cast<const bf16x8*>(
                    &As[(r << 6) + ((((ks << 2) + lg) ^ (r & 7)) << 3)]);
            }
            #pragma unroll
            for (int ni = 0; ni < 4; ++ni) {
                int r = wn * 64 + ni * 16 + lr;
                bfr[ni] = *reinterpret_cast<const bf16x8*>(
                    &Bs[(r << 6) + ((((ks << 2) + lg) ^ (r & 7)) << 3)]);
            }
            #pragma unroll
            for (int mi = 0; mi < 4; ++mi)
                #pragma unroll
                for (int ni = 0; ni < 4; ++ni)
                    acc[mi][ni] = __builtin_amdgcn_mfma_f32_16x16x32_bf16(
                        af[mi], bfr[ni], acc[mi][ni], 0, 0, 0);
        }
        __syncthreads();
    }

    #pragma unroll
    for (int mi = 0; mi < 4; ++mi) {
        #pragma unroll
        for (int rg = 0; rg < 4; ++rg) {
            int m = m0 + wm * 64 + mi * 16 + lg * 4 + rg;
            #pragma unroll
            for (int ni = 0; ni < 4; ++ni) {
                int n = n0 + wn * 64 + ni * 16 + lr;
                out[(size_t)m * DOUT + n] = acc[mi][ni][rg] + bo[n];
            }
        }
    }
}

// ---------------------------------------------------------------------------
extern "C" void kernel_launch(void* const* d_in, const int* in_sizes, int n_in,
                              void* d_out, int out_size, void* d_ws, size_t ws_size,
                              hipStream_t stream)
{
    const float* x  = (const float*)d_in[0];
    const float* wq = (const float*)d_in[1];
    const float* wk = (const float*)d_in[2];
    const float* wv = (const float*)d_in[3];
    const float* wo = (const float*)d_in[4];
    const float* bo = (const float*)d_in[5];
    float* out = (float*)d_out;

    const size_t N_X    = (size_t)BB * SS * DIN;        // 12,582,912
    const size_t N_W    = (size_t)DIN * DOUT;           // 589,824
    const size_t N_BHSD = (size_t)BB * NH * SS * HDIM;  // 12,582,912

    unsigned short* xb   = (unsigned short*)d_ws;
    unsigned short* wt   = xb   + N_X;
    unsigned short* wot  = wt   + 3 * N_W;
    unsigned short* qbuf = wot  + N_W;
    unsigned short* kbuf = qbuf + N_BHSD;
    unsigned short* vtb  = kbuf + N_BHSD;   // V^T (B,H,HD,S)
    unsigned short* ctxb = vtb  + N_BHSD;

    size_t need = (N_X + 4 * N_W + 4 * N_BHSD) * sizeof(unsigned short);
    if (ws_size < need) return;

    k_convert_x<<<4096, 256, 0, stream>>>(x, xb, (int)(N_X / 4));
    k_convert_w<<<dim3(12, 12, 4), 256, 0, stream>>>(wq, wk, wv, wo, wt, wot);
    k_qkv_gemm<<<dim3(128, 6, 3), 256, 0, stream>>>(xb, wt, qbuf, kbuf, vtb);
    k_attn<<<dim3(8, 192), 256, 0, stream>>>(qbuf, kbuf, vtb, ctxb);
    k_out_gemm<<<dim3(128, 6), 256, 0, stream>>>(ctxb, wot, bo, out);
}